// Round 3
// baseline (1171.033 us; speedup 1.0000x reference)
//
#include <hip/hip_runtime.h>
#include <hip/hip_fp16.h>

#define IMH 512
#define IMW 512
#define TW  32   // tile width  (x)
#define TH  16   // tile height (y)

// ---------------------------------------------------------------------------
// Fused LOI kernel, v4: register-fused alpha conv (no vv round-trip).
//
// v3 accounting: LDS issue was the serialized term (~3k cyc/block), split
// between phase D's 7 b128 reads per output point (no vertical reuse) and
// scalar b32 smooth passes. v4:
//   - tile 32x16 (halo ratio 836/512 = 1.63 vs 2.08)
//   - A2/A3: float4 units, 9 b128 reads / 4 points; A3 sliding register
//     window over 4 aligned b128 loads
//   - B: one thread = one point, all 8 bins -> 1 b32 read + 1 b128 write;
//     norm folded into vertical weights so iso = exp2(...) <= 1 (fp16-clean)
//   - C+D fused in registers: thread = (col, ng, rowquad). hh(r,c) is only
//     ever consumed by outputs in the SAME column, so a 4-row column strip
//     captures all vertical reuse: 10 hh rows x 7 b64 iso reads, hh in
//     __hfma2, vertical accumulate in f32 (norm-folded weights). No vv, one
//     barrier fewer.
// LDS ~17KB -> 8 blocks/CU (32 waves). All fused-phase LDS reads are
// lane-contiguous 512B/wave (conflict-free by construction).
// ---------------------------------------------------------------------------

__device__ __forceinline__ __half2 bc_h2(int v) {
  union { int i; __half2 h; } u; u.i = v; return u.h;
}
__device__ __forceinline__ int bc_i(__half2 v) {
  union { int i; __half2 h; } u; u.h = v; return u.i;
}

__global__ __launch_bounds__(256, 8) void loi_fused(
    const float* __restrict__ im,      // [512][512][3]
    const float* __restrict__ sigk,    // [2][9][9]
    const float* __restrict__ alphak,  // [3][7][7]
    const float* __restrict__ binc,    // [8]
    const float* __restrict__ betas,   // [2]
    float* __restrict__ out)           // [36][512][512][8]
{
  const int t     = threadIdx.x;
  const int combo = blockIdx.z;        // b*6 + s*3 + c
  const int b     = combo / 6;
  const int sc    = combo % 6;
  const int s     = sc / 3;
  const int c     = sc % 3;
  const int tx0   = blockIdx.x * TW;
  const int ty0   = blockIdx.y * TH;

  // smooth rows ty0-3..+18 (22), cols tx0-3..+34 (38 used, stride 40)
  __shared__ __align__(16) float smt[22 * 40];
  // phase A: imt[30][48] (5760B) + svt[22][48] (4224B) = 9984B
  // phase B+: iso[22][38][8] half = 13376B
  __shared__ __align__(16) unsigned char uni[13376];
  __shared__ float kf[3][8];    // alpha 1D factors (row sums of 2D kernels)
  __shared__ float sf[12];      // sigma 1D factors (9 used)

  float*  imt = (float*)uni;            // [30][48], 46 cols used, rest 0
  float*  svt = (float*)(uni + 5760);   // [22][48]
  __half* iso = (__half*)uni;           // [22][38][8]

  // --- A1: stage clipped image tile (zero outside image / beyond col 45) ---
  for (int e = t; e < 1440; e += 256) {
    int j = e / 48, i = e - j * 48;
    float v = 0.f;
    if (i < 46) {
      int gy = ty0 + j - 7, gx = tx0 + i - 7;
      if ((unsigned)gy < IMH && (unsigned)gx < IMW) {
        v = im[(gy * IMW + gx) * 3 + c];
        v = fminf(fmaxf(v, 0.f), 1.f);
      }
    }
    imt[e] = v;
  }
  // 1D separable factors (row sums; Gaussian kernels are exact outer products)
  if (t < 9) {
    float acc = 0.f;
    #pragma unroll
    for (int j = 0; j < 9; j++) acc += sigk[s * 81 + t * 9 + j];
    sf[t] = acc;
  }
  if (t >= 32 && t < 56) {
    int a = (t - 32) >> 3, d = t & 7;
    float v = 0.f;
    if (d < 7) {
      #pragma unroll
      for (int j = 0; j < 7; j++) v += alphak[a * 49 + d * 7 + j];
    }
    kf[a][d] = v;
  }
  __syncthreads();

  // --- A2: vertical 9-tap sigma smooth, float4 units (22 rows x 12 quads) ---
  for (int u = t; u < 264; u += 256) {
    int rr = u / 12, cu = u - rr * 12;
    const float* p = imt + rr * 48 + cu * 4;
    float4 acc = make_float4(0.f, 0.f, 0.f, 0.f);
    #pragma unroll
    for (int d = 0; d < 9; d++) {
      float4 w = *(const float4*)(p + d * 48);
      float sd = sf[d];
      acc.x = fmaf(sd, w.x, acc.x); acc.y = fmaf(sd, w.y, acc.y);
      acc.z = fmaf(sd, w.z, acc.z); acc.w = fmaf(sd, w.w, acc.w);
    }
    *(float4*)(svt + rr * 48 + cu * 4) = acc;
  }
  __syncthreads();

  // --- A3: horizontal 9-tap, sliding register window (22 rows x 10 quads) ---
  for (int u = t; u < 220; u += 256) {
    int rr = u / 10, cu = u - rr * 10;
    const float* p = svt + rr * 48 + cu * 4;
    float v[16];
    #pragma unroll
    for (int q = 0; q < 4; q++) {
      float4 w = *(const float4*)(p + q * 4);
      v[4 * q + 0] = w.x; v[4 * q + 1] = w.y;
      v[4 * q + 2] = w.z; v[4 * q + 3] = w.w;
    }
    float o0 = 0.f, o1 = 0.f, o2 = 0.f, o3 = 0.f;
    #pragma unroll
    for (int d = 0; d < 9; d++) {
      float sd = sf[d];
      o0 = fmaf(sd, v[d + 0], o0); o1 = fmaf(sd, v[d + 1], o1);
      o2 = fmaf(sd, v[d + 2], o2); o3 = fmaf(sd, v[d + 3], o3);
    }
    *(float4*)(smt + rr * 40 + cu * 4) = make_float4(o0, o1, o2, o3);
  }
  __syncthreads();

  // --- B: iso[22][38][8] = valid * exp2(c2*(sm-ctr)^2)  (norm folded later) ---
  const float beta = betas[b];
  const float c2   = -0.72134752044448170f / (beta * beta); // -0.5*log2e/b^2
  float bc0 = binc[0], bc1 = binc[1], bc2 = binc[2], bc3 = binc[3];
  float bc4 = binc[4], bc5 = binc[5], bc6 = binc[6], bc7 = binc[7];
  for (int p = t; p < 836; p += 256) {
    int rr = p / 38, jj = p - rr * 38;
    float v = smt[rr * 40 + jj];
    int X = tx0 + jj - 3, Y = ty0 + rr - 3;   // ref zero-pads iso
    float msk = (((unsigned)X < IMW) && ((unsigned)Y < IMH)) ? 1.f : 0.f;
    float t0 = v - bc0, t1 = v - bc1, t2 = v - bc2, t3 = v - bc3;
    float t4 = v - bc4, t5 = v - bc5, t6 = v - bc6, t7 = v - bc7;
    float E0 = exp2f(t0 * t0 * c2) * msk, E1 = exp2f(t1 * t1 * c2) * msk;
    float E2 = exp2f(t2 * t2 * c2) * msk, E3 = exp2f(t3 * t3 * c2) * msk;
    float E4 = exp2f(t4 * t4 * c2) * msk, E5 = exp2f(t5 * t5 * c2) * msk;
    float E6 = exp2f(t6 * t6 * c2) * msk, E7 = exp2f(t7 * t7 * c2) * msk;
    int4 w;
    w.x = bc_i(__floats2half2_rn(E0, E1));
    w.y = bc_i(__floats2half2_rn(E2, E3));
    w.z = bc_i(__floats2half2_rn(E4, E5));
    w.w = bc_i(__floats2half2_rn(E6, E7));
    *(int4*)(iso + p * 8) = w;
  }
  __syncthreads();

  // --- fused C+D: hh in __hfma2, vertical accumulate in f32 ---
  const float norm = 0.39894228040143268f / beta;   // 1/(sqrt(2pi)*beta)
  __half2 kh[3][7];
  float   kvf[3][7];
  #pragma unroll
  for (int a = 0; a < 3; a++)
    #pragma unroll
    for (int d = 0; d < 7; d++) {
      float f = kf[a][d];
      kh[a][d]  = __float2half2_rn(f);
      kvf[a][d] = f * norm;          // norm applied exactly once, in f32
    }

  const int ng  = t & 1;             // n-half: bins 4*ng..4*ng+3
  const int col = (t >> 1) & 31;
  const int rq  = t >> 6;            // wave id = row quad
  const int r0  = rq * 4;

  float4 acc[4][3];
  #pragma unroll
  for (int j = 0; j < 4; j++)
    #pragma unroll
    for (int a = 0; a < 3; a++) acc[j][a] = make_float4(0.f, 0.f, 0.f, 0.f);

  const __half* ibase = iso + ((r0 * 38 + col) * 8 + ng * 4);
  #pragma unroll
  for (int m = 0; m < 10; m++) {             // hh row = out row r0 + m - 3  taps
    const __half* prow = ibase + m * 304;    // 38*8
    __half2 h0[3], h1[3];
    #pragma unroll
    for (int a = 0; a < 3; a++) {
      h0[a] = __float2half2_rn(0.f);
      h1[a] = __float2half2_rn(0.f);
    }
    #pragma unroll
    for (int e = 0; e < 7; e++) {
      int2 ve = *(const int2*)(prow + e * 8);
      __half2 lo = bc_h2(ve.x), hi = bc_h2(ve.y);
      #pragma unroll
      for (int a = 0; a < 3; a++) {
        h0[a] = __hfma2(kh[a][e], lo, h0[a]);
        h1[a] = __hfma2(kh[a][e], hi, h1[a]);
      }
    }
    #pragma unroll
    for (int a = 0; a < 3; a++) {
      float2 f0 = __half22float2(h0[a]);
      float2 f1 = __half22float2(h1[a]);
      #pragma unroll
      for (int j = 0; j < 4; j++) {
        if (m - j >= 0 && m - j <= 6) {      // compile-time after unroll
          float w = kvf[a][m - j];
          acc[j][a].x = fmaf(w, f0.x, acc[j][a].x);
          acc[j][a].y = fmaf(w, f0.y, acc[j][a].y);
          acc[j][a].z = fmaf(w, f1.x, acc[j][a].z);
          acc[j][a].w = fmaf(w, f1.y, acc[j][a].w);
        }
      }
    }
  }

  // --- stores: float4, wave = contiguous 1KB per instr ---
  const int gx = tx0 + col;
  #pragma unroll
  for (int j = 0; j < 4; j++) {
    const int gy = ty0 + r0 + j;
    float* op = out + ((size_t)combo << 21)
                    + ((size_t)gy * 512 + gx) * 8 + ng * 4;
    *(float4*)op                          = acc[j][0];
    *(float4*)(op + ((size_t)12 << 21))   = acc[j][1];
    *(float4*)(op + ((size_t)24 << 21))   = acc[j][2];
  }
}

extern "C" void kernel_launch(void* const* d_in, const int* in_sizes, int n_in,
                              void* d_out, int out_size, void* d_ws, size_t ws_size,
                              hipStream_t stream)
{
  const float* im   = (const float*)d_in[0];   // (512,512,3)
  const float* sigk = (const float*)d_in[1];   // (2,9,9)
  const float* alpk = (const float*)d_in[2];   // (3,7,7)
  const float* binc = (const float*)d_in[3];   // (8,)
  const float* bets = (const float*)d_in[4];   // (2,)
  float* out = (float*)d_out;                  // (3,2,2,3,512,512,8)

  loi_fused<<<dim3(512 / TW, 512 / TH, 12), 256, 0, stream>>>(
      im, sigk, alpk, binc, bets, out);
}

// Round 4
// 549.850 us; speedup vs baseline: 2.1297x; 2.1297x over previous
//
#include <hip/hip_runtime.h>
#include <hip/hip_fp16.h>

#define IMH 512
#define IMW 512
#define TW  32   // tile width  (x)
#define TH  16   // tile height (y)

// ---------------------------------------------------------------------------
// Fused LOI kernel, v5: v4 dataflow with the register budget FIXED.
//
// v4 post-mortem: __launch_bounds__(256, 8) = 8 waves/SIMD min = 64-VGPR cap.
// Fused C+D needs ~110 live VGPRs (acc[4][3] float4 alone is 48) -> compiler
// spilled to scratch: VGPR_Count=32, FETCH 1.5GB / WRITE 1.8GB of scratch
// traffic, 920us. v5: __launch_bounds__(256, 4) -> 128-VGPR budget, no
// spill, 4 blocks/CU (16 waves). Everything else unchanged:
//   - tile 32x16, halo ratio 1.63
//   - A2/A3 smooth in float4 units, sliding register window
//   - B: one thread = one point, all 8 bins, 1 b32 read + 1 b128 write;
//     iso = exp2(...) <= 1 (norm folded into f32 vertical weights)
//   - C+D fused in registers: thread = (col, ng, rowquad); 10 hh rows x
//     7 b64 iso reads each; hh in __hfma2; vertical accumulate in f32.
// LDS ~17KB. All fused-phase LDS reads lane-contiguous 512B/wave.
// ---------------------------------------------------------------------------

__device__ __forceinline__ __half2 bc_h2(int v) {
  union { int i; __half2 h; } u; u.i = v; return u.h;
}
__device__ __forceinline__ int bc_i(__half2 v) {
  union { int i; __half2 h; } u; u.h = v; return u.i;
}

__global__ __launch_bounds__(256, 4) void loi_fused(
    const float* __restrict__ im,      // [512][512][3]
    const float* __restrict__ sigk,    // [2][9][9]
    const float* __restrict__ alphak,  // [3][7][7]
    const float* __restrict__ binc,    // [8]
    const float* __restrict__ betas,   // [2]
    float* __restrict__ out)           // [36][512][512][8]
{
  const int t     = threadIdx.x;
  const int combo = blockIdx.z;        // b*6 + s*3 + c
  const int b     = combo / 6;
  const int sc    = combo % 6;
  const int s     = sc / 3;
  const int c     = sc % 3;
  const int tx0   = blockIdx.x * TW;
  const int ty0   = blockIdx.y * TH;

  // smooth rows ty0-3..+18 (22), cols tx0-3..+34 (38 used, stride 40)
  __shared__ __align__(16) float smt[22 * 40];
  // phase A: imt[30][48] (5760B) + svt[22][48] (4224B) = 9984B
  // phase B+: iso[22][38][8] half = 13376B
  __shared__ __align__(16) unsigned char uni[13376];
  __shared__ float kf[3][8];    // alpha 1D factors (row sums of 2D kernels)
  __shared__ float sf[12];      // sigma 1D factors (9 used)

  float*  imt = (float*)uni;            // [30][48], 46 cols used, rest 0
  float*  svt = (float*)(uni + 5760);   // [22][48]
  __half* iso = (__half*)uni;           // [22][38][8]

  // --- A1: stage clipped image tile (zero outside image / beyond col 45) ---
  for (int e = t; e < 1440; e += 256) {
    int j = e / 48, i = e - j * 48;
    float v = 0.f;
    if (i < 46) {
      int gy = ty0 + j - 7, gx = tx0 + i - 7;
      if ((unsigned)gy < IMH && (unsigned)gx < IMW) {
        v = im[(gy * IMW + gx) * 3 + c];
        v = fminf(fmaxf(v, 0.f), 1.f);
      }
    }
    imt[e] = v;
  }
  // 1D separable factors (row sums; Gaussian kernels are exact outer products)
  if (t < 9) {
    float acc = 0.f;
    #pragma unroll
    for (int j = 0; j < 9; j++) acc += sigk[s * 81 + t * 9 + j];
    sf[t] = acc;
  }
  if (t >= 32 && t < 56) {
    int a = (t - 32) >> 3, d = t & 7;
    float v = 0.f;
    if (d < 7) {
      #pragma unroll
      for (int j = 0; j < 7; j++) v += alphak[a * 49 + d * 7 + j];
    }
    kf[a][d] = v;
  }
  __syncthreads();

  // --- A2: vertical 9-tap sigma smooth, float4 units (22 rows x 12 quads) ---
  for (int u = t; u < 264; u += 256) {
    int rr = u / 12, cu = u - rr * 12;
    const float* p = imt + rr * 48 + cu * 4;
    float4 acc = make_float4(0.f, 0.f, 0.f, 0.f);
    #pragma unroll
    for (int d = 0; d < 9; d++) {
      float4 w = *(const float4*)(p + d * 48);
      float sd = sf[d];
      acc.x = fmaf(sd, w.x, acc.x); acc.y = fmaf(sd, w.y, acc.y);
      acc.z = fmaf(sd, w.z, acc.z); acc.w = fmaf(sd, w.w, acc.w);
    }
    *(float4*)(svt + rr * 48 + cu * 4) = acc;
  }
  __syncthreads();

  // --- A3: horizontal 9-tap, sliding register window (22 rows x 10 quads) ---
  for (int u = t; u < 220; u += 256) {
    int rr = u / 10, cu = u - rr * 10;
    const float* p = svt + rr * 48 + cu * 4;
    float v[16];
    #pragma unroll
    for (int q = 0; q < 4; q++) {
      float4 w = *(const float4*)(p + q * 4);
      v[4 * q + 0] = w.x; v[4 * q + 1] = w.y;
      v[4 * q + 2] = w.z; v[4 * q + 3] = w.w;
    }
    float o0 = 0.f, o1 = 0.f, o2 = 0.f, o3 = 0.f;
    #pragma unroll
    for (int d = 0; d < 9; d++) {
      float sd = sf[d];
      o0 = fmaf(sd, v[d + 0], o0); o1 = fmaf(sd, v[d + 1], o1);
      o2 = fmaf(sd, v[d + 2], o2); o3 = fmaf(sd, v[d + 3], o3);
    }
    *(float4*)(smt + rr * 40 + cu * 4) = make_float4(o0, o1, o2, o3);
  }
  __syncthreads();

  // --- B: iso[22][38][8] = valid * exp2(c2*(sm-ctr)^2)  (norm folded later) ---
  const float beta = betas[b];
  const float c2   = -0.72134752044448170f / (beta * beta); // -0.5*log2e/b^2
  float bc0 = binc[0], bc1 = binc[1], bc2 = binc[2], bc3 = binc[3];
  float bc4 = binc[4], bc5 = binc[5], bc6 = binc[6], bc7 = binc[7];
  for (int p = t; p < 836; p += 256) {
    int rr = p / 38, jj = p - rr * 38;
    float v = smt[rr * 40 + jj];
    int X = tx0 + jj - 3, Y = ty0 + rr - 3;   // ref zero-pads iso
    float msk = (((unsigned)X < IMW) && ((unsigned)Y < IMH)) ? 1.f : 0.f;
    float t0 = v - bc0, t1 = v - bc1, t2 = v - bc2, t3 = v - bc3;
    float t4 = v - bc4, t5 = v - bc5, t6 = v - bc6, t7 = v - bc7;
    float E0 = exp2f(t0 * t0 * c2) * msk, E1 = exp2f(t1 * t1 * c2) * msk;
    float E2 = exp2f(t2 * t2 * c2) * msk, E3 = exp2f(t3 * t3 * c2) * msk;
    float E4 = exp2f(t4 * t4 * c2) * msk, E5 = exp2f(t5 * t5 * c2) * msk;
    float E6 = exp2f(t6 * t6 * c2) * msk, E7 = exp2f(t7 * t7 * c2) * msk;
    int4 w;
    w.x = bc_i(__floats2half2_rn(E0, E1));
    w.y = bc_i(__floats2half2_rn(E2, E3));
    w.z = bc_i(__floats2half2_rn(E4, E5));
    w.w = bc_i(__floats2half2_rn(E6, E7));
    *(int4*)(iso + p * 8) = w;
  }
  __syncthreads();

  // --- fused C+D: hh in __hfma2, vertical accumulate in f32 ---
  const float norm = 0.39894228040143268f / beta;   // 1/(sqrt(2pi)*beta)
  __half2 kh[3][7];
  float   kvf[3][7];
  #pragma unroll
  for (int a = 0; a < 3; a++)
    #pragma unroll
    for (int d = 0; d < 7; d++) {
      float f = kf[a][d];
      kh[a][d]  = __float2half2_rn(f);
      kvf[a][d] = f * norm;          // norm applied exactly once, in f32
    }

  const int ng  = t & 1;             // n-half: bins 4*ng..4*ng+3
  const int col = (t >> 1) & 31;
  const int rq  = t >> 6;            // wave id = row quad
  const int r0  = rq * 4;

  float4 acc[4][3];
  #pragma unroll
  for (int j = 0; j < 4; j++)
    #pragma unroll
    for (int a = 0; a < 3; a++) acc[j][a] = make_float4(0.f, 0.f, 0.f, 0.f);

  const __half* ibase = iso + ((r0 * 38 + col) * 8 + ng * 4);
  #pragma unroll
  for (int m = 0; m < 10; m++) {             // hh row = out row r0 + m - 3
    const __half* prow = ibase + m * 304;    // 38*8
    __half2 h0[3], h1[3];
    #pragma unroll
    for (int a = 0; a < 3; a++) {
      h0[a] = __float2half2_rn(0.f);
      h1[a] = __float2half2_rn(0.f);
    }
    #pragma unroll
    for (int e = 0; e < 7; e++) {
      int2 ve = *(const int2*)(prow + e * 8);
      __half2 lo = bc_h2(ve.x), hi = bc_h2(ve.y);
      #pragma unroll
      for (int a = 0; a < 3; a++) {
        h0[a] = __hfma2(kh[a][e], lo, h0[a]);
        h1[a] = __hfma2(kh[a][e], hi, h1[a]);
      }
    }
    #pragma unroll
    for (int a = 0; a < 3; a++) {
      float2 f0 = __half22float2(h0[a]);
      float2 f1 = __half22float2(h1[a]);
      #pragma unroll
      for (int j = 0; j < 4; j++) {
        if (m - j >= 0 && m - j <= 6) {      // compile-time after unroll
          float w = kvf[a][m - j];
          acc[j][a].x = fmaf(w, f0.x, acc[j][a].x);
          acc[j][a].y = fmaf(w, f0.y, acc[j][a].y);
          acc[j][a].z = fmaf(w, f1.x, acc[j][a].z);
          acc[j][a].w = fmaf(w, f1.y, acc[j][a].w);
        }
      }
    }
  }

  // --- stores: float4, wave = contiguous 1KB per instr ---
  const int gx = tx0 + col;
  #pragma unroll
  for (int j = 0; j < 4; j++) {
    const int gy = ty0 + r0 + j;
    float* op = out + ((size_t)combo << 21)
                    + ((size_t)gy * 512 + gx) * 8 + ng * 4;
    *(float4*)op                          = acc[j][0];
    *(float4*)(op + ((size_t)12 << 21))   = acc[j][1];
    *(float4*)(op + ((size_t)24 << 21))   = acc[j][2];
  }
}

extern "C" void kernel_launch(void* const* d_in, const int* in_sizes, int n_in,
                              void* d_out, int out_size, void* d_ws, size_t ws_size,
                              hipStream_t stream)
{
  const float* im   = (const float*)d_in[0];   // (512,512,3)
  const float* sigk = (const float*)d_in[1];   // (2,9,9)
  const float* alpk = (const float*)d_in[2];   // (3,7,7)
  const float* binc = (const float*)d_in[3];   // (8,)
  const float* bets = (const float*)d_in[4];   // (2,)
  float* out = (float*)d_out;                  // (3,2,2,3,512,512,8)

  loi_fused<<<dim3(512 / TW, 512 / TH, 12), 256, 0, stream>>>(
      im, sigk, alpk, binc, bets, out);
}